// Round 1
// baseline (543.662 us; speedup 1.0000x reference)
//
#include <hip/hip_runtime.h>

typedef unsigned short u16;
typedef short s16x8 __attribute__((ext_vector_type(8)));
typedef float f32x4 __attribute__((ext_vector_type(4)));

#define B_  8
#define S_  4096
#define D_  128
#define BM  64     // q rows per block (4 waves x 16)
#define KT  32     // keys per inner iteration

__device__ __forceinline__ u16 f2bf(float f) {
  union { float f; unsigned u; } v; v.f = f;
  unsigned r = v.u + 0x7fffu + ((v.u >> 16) & 1u);  // RNE
  return (u16)(r >> 16);
}

// ---------------------------------------------------------------- proj: q = x @ W (fp32 vector, bf16 out)
__global__ __launch_bounds__(256) void proj_kernel(
    const float* __restrict__ x,   // [B*S][128]
    const float* __restrict__ W,   // [128][128]
    u16* __restrict__ q)           // bf16 [B*S][128]
{
  __shared__ float xs[16][128];
  int row0 = blockIdx.x * 16;
  int tid = threadIdx.x;
#pragma unroll
  for (int i = 0; i < 8; ++i) {
    int idx = tid + i * 256;
    xs[idx >> 7][idx & 127] = x[(size_t)row0 * 128 + idx];
  }
  __syncthreads();
  int col = tid & 127;
  int rg  = tid >> 7;            // 0..1 -> rows rg*8 .. rg*8+7
  float acc[8];
#pragma unroll
  for (int r = 0; r < 8; ++r) acc[r] = 0.f;
  for (int k = 0; k < 128; ++k) {
    float w = W[k * 128 + col];  // coalesced, L1/L2 cached (64 KB)
#pragma unroll
    for (int r = 0; r < 8; ++r)
      acc[r] += xs[rg * 8 + r][k] * w;   // LDS broadcast
  }
#pragma unroll
  for (int r = 0; r < 8; ++r)
    q[(size_t)(row0 + rg * 8 + r) * 128 + col] = f2bf(acc[r]);
}

// ---------------------------------------------------------------- transpose: vT[b][d][t] = bf16(x[b][t][d])
__global__ __launch_bounds__(256) void transpose_kernel(
    const float* __restrict__ x,   // [B][S][128]
    u16* __restrict__ vT)          // bf16 [B][128][S]
{
  __shared__ u16 tile[64][130];    // +2 pad: conflict-light
  int b  = blockIdx.x >> 6;
  int t0 = (blockIdx.x & 63) * 64;
  int tid = threadIdx.x;
  const float* xb = x + ((size_t)b * S_ + t0) * D_;
#pragma unroll
  for (int i = 0; i < 32; ++i) {
    int idx = tid + i * 256;
    tile[idx >> 7][idx & 127] = f2bf(xb[idx]);   // coalesced fp32 read
  }
  __syncthreads();
  u16* ob = vT + (size_t)b * D_ * S_ + t0;
#pragma unroll
  for (int i = 0; i < 32; ++i) {
    int idx = tid + i * 256;
    int d = idx >> 6, t = idx & 63;
    ob[(size_t)d * S_ + t] = tile[t][d];         // coalesced 128B segments
  }
}

// ---------------------------------------------------------------- flash attention
// Q=K=qb (bf16), V=vT (bf16, [D][S]), out fp32. Per-wave 16 q-rows, 32-key tiles.
__global__ __launch_bounds__(256) void flash_kernel(
    const u16* __restrict__ qb, const u16* __restrict__ vT,
    float* __restrict__ out)
{
  __shared__ __align__(16) u16 p_lds[4][16][40];   // per-wave 16x32 P tile, padded stride 40
  int blk  = blockIdx.x;
  int b    = blk >> 6;
  int m0   = (blk & 63) * BM;
  int tid  = threadIdx.x;
  int wave = tid >> 6, lane = tid & 63;
  int quad = lane >> 4, l16 = lane & 15;

  const u16* qbase = qb + (size_t)b * S_ * D_;
  const u16* vbase = vT + (size_t)b * D_ * S_;

  // Q A-frags (A[m=l16][k=quad*8+j], 4 frags cover k=0..127)
  int qrow = m0 + wave * 16 + l16;
  s16x8 qfrag[4];
#pragma unroll
  for (int f = 0; f < 4; ++f)
    qfrag[f] = *(const s16x8*)(qbase + (size_t)qrow * D_ + f * 32 + quad * 8);

  float m_i[4], l_i[4];
#pragma unroll
  for (int r = 0; r < 4; ++r) { m_i[r] = -3.0e38f; l_i[r] = 0.f; }
  f32x4 o_acc[8];
#pragma unroll
  for (int t = 0; t < 8; ++t) o_acc[t] = (f32x4){0.f, 0.f, 0.f, 0.f};

  u16* myP = &p_lds[wave][0][0];

  for (int k0 = 0; k0 < S_; k0 += KT) {
    // --- prefetch K frags (B-op: n=l16 key, k=quad*8+j over D) and V frags (B-op: k=quad*8+j key, n=l16 d)
    s16x8 kf[2][4];
#pragma unroll
    for (int h = 0; h < 2; ++h) {
      const u16* kr = qbase + (size_t)(k0 + h * 16 + l16) * D_ + quad * 8;
#pragma unroll
      for (int f = 0; f < 4; ++f)
        kf[h][f] = *(const s16x8*)(kr + f * 32);
    }
    s16x8 vf[8];
#pragma unroll
    for (int t = 0; t < 8; ++t)
      vf[t] = *(const s16x8*)(vbase + (size_t)(t * 16 + l16) * S_ + k0 + quad * 8);

    // --- S = Q K^T : two 16x16 tiles, K=128 via 4 MFMAs each
    f32x4 s0 = (f32x4){0.f,0.f,0.f,0.f}, s1 = (f32x4){0.f,0.f,0.f,0.f};
#pragma unroll
    for (int f = 0; f < 4; ++f)
      s0 = __builtin_amdgcn_mfma_f32_16x16x32_bf16(qfrag[f], kf[0][f], s0, 0, 0, 0);
#pragma unroll
    for (int f = 0; f < 4; ++f)
      s1 = __builtin_amdgcn_mfma_f32_16x16x32_bf16(qfrag[f], kf[1][f], s1, 0, 0, 0);

    // --- online softmax; row = quad*4+r, col = l16 (16 lanes of this quad)
    float mx[4];
#pragma unroll
    for (int r = 0; r < 4; ++r) mx[r] = fmaxf(s0[r], s1[r]);
#pragma unroll
    for (int off = 8; off >= 1; off >>= 1)
#pragma unroll
      for (int r = 0; r < 4; ++r)
        mx[r] = fmaxf(mx[r], __shfl_xor(mx[r], off, 64));

    float alpha[4], rs[4], p0[4], p1[4];
#pragma unroll
    for (int r = 0; r < 4; ++r) {
      float mn = fmaxf(m_i[r], mx[r]);
      alpha[r] = __expf(m_i[r] - mn);
      m_i[r]  = mn;
      p0[r] = __expf(s0[r] - mn);
      p1[r] = __expf(s1[r] - mn);
      rs[r] = p0[r] + p1[r];
    }
#pragma unroll
    for (int off = 8; off >= 1; off >>= 1)
#pragma unroll
      for (int r = 0; r < 4; ++r)
        rs[r] += __shfl_xor(rs[r], off, 64);
#pragma unroll
    for (int r = 0; r < 4; ++r) l_i[r] = l_i[r] * alpha[r] + rs[r];
#pragma unroll
    for (int t = 0; t < 8; ++t)
#pragma unroll
      for (int r = 0; r < 4; ++r)
        o_acc[t][r] *= alpha[r];

    // --- P: C-layout -> LDS -> A-layout (per-wave region; DS ops in-order within a wave)
#pragma unroll
    for (int r = 0; r < 4; ++r) {
      myP[(quad * 4 + r) * 40 + l16]      = f2bf(p0[r]);
      myP[(quad * 4 + r) * 40 + 16 + l16] = f2bf(p1[r]);
    }
    __asm__ volatile("s_waitcnt lgkmcnt(0)" ::: "memory");
    s16x8 pf = *(const s16x8*)(myP + l16 * 40 + quad * 8);

    // --- O += P V : 8 d-tiles, K=32
#pragma unroll
    for (int t = 0; t < 8; ++t)
      o_acc[t] = __builtin_amdgcn_mfma_f32_16x16x32_bf16(pf, vf[t], o_acc[t], 0, 0, 0);
  }

  // --- epilogue: normalize, write fp32
  float* obase = out + ((size_t)b * S_ + m0 + wave * 16) * D_;
#pragma unroll
  for (int r = 0; r < 4; ++r) {
    float inv = 1.f / l_i[r];
    float* orow = obase + (size_t)(quad * 4 + r) * D_;
#pragma unroll
    for (int t = 0; t < 8; ++t)
      orow[t * 16 + l16] = o_acc[t][r] * inv;
  }
}

// ---------------------------------------------------------------- launch
extern "C" void kernel_launch(void* const* d_in, const int* in_sizes, int n_in,
                              void* d_out, int out_size, void* d_ws, size_t ws_size,
                              hipStream_t stream) {
  const float* x = (const float*)d_in[0];
  const float* W = (const float*)d_in[1];
  // d_in[2] = b (unused by reference)
  float* out = (float*)d_out;

  u16* qb = (u16*)d_ws;                       // bf16 q: 8 MB
  u16* vT = qb + (size_t)B_ * S_ * D_;        // bf16 x^T: 8 MB

  proj_kernel<<<(B_ * S_) / 16, 256, 0, stream>>>(x, W, qb);
  transpose_kernel<<<B_ * (S_ / 64), 256, 0, stream>>>(x, vT);
  flash_kernel<<<B_ * (S_ / BM), 256, 0, stream>>>(qb, vT, out);
}